// Round 6
// baseline (601.255 us; speedup 1.0000x reference)
//
#include <hip/hip_runtime.h>
#include <stdint.h>

#define T_TOK 8192
#define H_DIM 1024
#define E_NUM 8
#define F_DIM 2048
#define BATCH 4
#define AUX_COEF 0.001f
#define Z_COEF 0.001f

#define NBLK_TOK 32       // blocks for hist/scatter (8192/256)

// ---- grouped GEMM params: 128x128 tile, 4 waves, 2 blocks/CU co-resident ----
#define GBM 128
#define GBN 128
#define GBK 64
#define MT_CAP 18         // 18*128 = 2304 rows capacity per expert (counts ~2048±55)

typedef __bf16 bf16x8 __attribute__((ext_vector_type(8)));
typedef float f32x4 __attribute__((ext_vector_type(4)));

__device__ __forceinline__ unsigned short f2bf(float f) {
    union { float f; uint32_t u; } v; v.f = f;
    uint32_t u = v.u;
    return (unsigned short)((u + 0x7FFFu + ((u >> 16) & 1u)) >> 16);
}
__device__ __forceinline__ float bf2f(unsigned short u) {
    union { uint32_t u; float f; } v; v.u = ((uint32_t)u) << 16; return v.f;
}

// async global->LDS, 16 B per lane; LDS dest = wave-uniform base + lane*16
__device__ __forceinline__ void gl_lds16(const void* g, void* l) {
    __builtin_amdgcn_global_load_lds((const __attribute__((address_space(1))) uint32_t*)g,
                                     (__attribute__((address_space(3))) uint32_t*)l, 16, 0, 0);
}

// ------------- transpose+convert: in [E,R,C] fp32 -> out [E,C,R] bf16 -------------
__global__ void transpose_conv_kernel(const float* __restrict__ in, unsigned short* __restrict__ out,
                                      int R, int C) {
    __shared__ float tile[32][33];
    int e = blockIdx.z;
    const float* ine = in + (size_t)e * R * C;
    unsigned short* oute = out + (size_t)e * R * C;
    int tx = threadIdx.x & 31, ty = threadIdx.x >> 5;  // 32x8
    int c0 = blockIdx.x * 32, r0 = blockIdx.y * 32;
#pragma unroll
    for (int i = 0; i < 4; i++) {
        int r = r0 + ty + i * 8;
        tile[ty + i * 8][tx] = ine[(size_t)r * C + c0 + tx];
    }
    __syncthreads();
#pragma unroll
    for (int i = 0; i < 4; i++) {
        int c = c0 + ty + i * 8;
        oute[(size_t)c * R + r0 + tx] = f2bf(tile[tx][ty + i * 8]);
    }
}

// ------- router (fused x->bf16 convert): logits, losses (block-partial), top-2 -------
__global__ void router_kernel(const float* __restrict__ x, const float* __restrict__ rw,
                              unsigned short* __restrict__ xb,
                              int* __restrict__ top2, float2* __restrict__ loss_part) {
    int wave = threadIdx.x >> 6;
    int lane = threadIdx.x & 63;
    int t = blockIdx.x * 4 + wave;
    const float4* xr = (const float4*)(x + (size_t)t * H_DIM);
    float4 xv[4];
#pragma unroll
    for (int k = 0; k < 4; k++) xv[k] = xr[lane + 64 * k];
    uint2* xo = (uint2*)(xb + (size_t)t * H_DIM);
#pragma unroll
    for (int k = 0; k < 4; k++) {
        uint2 o;
        o.x = (uint32_t)f2bf(xv[k].x) | ((uint32_t)f2bf(xv[k].y) << 16);
        o.y = (uint32_t)f2bf(xv[k].z) | ((uint32_t)f2bf(xv[k].w) << 16);
        xo[lane + 64 * k] = o;
    }
    float acc[E_NUM];
#pragma unroll
    for (int e = 0; e < E_NUM; e++) {
        const float4* rr = (const float4*)(rw + e * H_DIM);
        float s = 0.f;
#pragma unroll
        for (int k = 0; k < 4; k++) {
            float4 r = rr[lane + 64 * k];
            s += xv[k].x * r.x + xv[k].y * r.y + xv[k].z * r.z + xv[k].w * r.w;
        }
        acc[e] = s;
    }
#pragma unroll
    for (int e = 0; e < E_NUM; e++) {
        float v = acc[e];
#pragma unroll
        for (int off = 32; off; off >>= 1) v += __shfl_xor(v, off);
        acc[e] = v;
    }
    __shared__ float red[8];
    if (lane == 0) {
        float mx = acc[0];
#pragma unroll
        for (int e = 1; e < E_NUM; e++) mx = fmaxf(mx, acc[e]);
        float s = 0.f;
#pragma unroll
        for (int e = 0; e < E_NUM; e++) s += expf(acc[e] - mx);
        float lse = mx + logf(s);
        float slogp = 0.f, ssq = 0.f;
#pragma unroll
        for (int e = 0; e < E_NUM; e++) { slogp += acc[e] - lse; ssq += acc[e] * acc[e]; }
        int i1 = 0; float m1 = acc[0];
#pragma unroll
        for (int e = 1; e < E_NUM; e++) if (acc[e] > m1) { m1 = acc[e]; i1 = e; }
        int i2 = -1; float m2 = -1e30f;
#pragma unroll
        for (int e = 0; e < E_NUM; e++) if (e != i1 && acc[e] > m2) { m2 = acc[e]; i2 = e; }
        top2[t] = i1 | (i2 << 8);
        red[wave] = slogp;
        red[4 + wave] = ssq;
    }
    __syncthreads();
    if (threadIdx.x == 0) {
        float2 p;
        p.x = red[0] + red[1] + red[2] + red[3];
        p.y = red[4] + red[5] + red[6] + red[7];
        loss_part[blockIdx.x] = p;
    }
}

// ---------------- histogram: per-block expert counts (LDS bins) ----------------
__global__ void hist_kernel(const int* __restrict__ top2, int* __restrict__ blockcounts) {
    __shared__ int cnt[E_NUM];
    if (threadIdx.x < E_NUM) cnt[threadIdx.x] = 0;
    __syncthreads();
    int t = blockIdx.x * 256 + threadIdx.x;
    int v = top2[t];
    atomicAdd(&cnt[v & 255], 1);
    atomicAdd(&cnt[v >> 8], 1);
    __syncthreads();
    if (threadIdx.x < E_NUM) blockcounts[blockIdx.x * E_NUM + threadIdx.x] = cnt[threadIdx.x];
}

// ---------------- scan + loss finalize (1 block) ----------------
__global__ void scan_kernel(const int* __restrict__ blockcounts, const float2* __restrict__ loss_part,
                            int* __restrict__ counts, int* __restrict__ basep, int* __restrict__ offs,
                            float* __restrict__ loss_out) {
    __shared__ float redx[4], redy[4];
    int tid = threadIdx.x;
    float sx = 0.f, sy = 0.f;
    for (int i = tid; i < T_TOK / 4; i += 256) {
        float2 p = loss_part[i];
        sx += p.x; sy += p.y;
    }
#pragma unroll
    for (int off = 32; off; off >>= 1) { sx += __shfl_xor(sx, off); sy += __shfl_xor(sy, off); }
    if ((tid & 63) == 0) { redx[tid >> 6] = sx; redy[tid >> 6] = sy; }
    __syncthreads();
    if (tid == 0) {
        float slogp = redx[0] + redx[1] + redx[2] + redx[3];
        float ssq = redy[0] + redy[1] + redy[2] + redy[3];
        float ideal = 1.0f / E_NUM;
        float aux = ideal * ((float)T_TOK * E_NUM * logf(ideal) - slogp) / BATCH * AUX_COEF;
        float z = ssq / ((float)T_TOK * E_NUM) * Z_COEF;
        loss_out[0] = aux + z;
    }
    if (tid < E_NUM) {
        int s = 0;
        for (int b = 0; b < NBLK_TOK; b++) s += blockcounts[b * E_NUM + tid];
        counts[tid] = s;
    }
    __syncthreads();
    if (tid == 0) {
        int s = 0;
        for (int e = 0; e < E_NUM; e++) { basep[e] = s; s += counts[e]; }
    }
    __syncthreads();
    if (tid < E_NUM) {
        int o = basep[tid];
        for (int b = 0; b < NBLK_TOK; b++) { offs[b * E_NUM + tid] = o; o += blockcounts[b * E_NUM + tid]; }
    }
}

// -------- scatter: LDS cursors + per-block offsets; record each token's 2 positions --------
__global__ void scatter_kernel(const int* __restrict__ top2, const int* __restrict__ offs,
                               int* __restrict__ rowlist, int* __restrict__ posv) {
    __shared__ int cur[E_NUM];
    if (threadIdx.x < E_NUM) cur[threadIdx.x] = 0;
    __syncthreads();
    int t = blockIdx.x * 256 + threadIdx.x;
    int v = top2[t];
    int e0 = v & 255, e1 = v >> 8;
    int r0 = atomicAdd(&cur[e0], 1);
    int r1 = atomicAdd(&cur[e1], 1);
    int p0 = offs[blockIdx.x * E_NUM + e0] + r0;
    int p1 = offs[blockIdx.x * E_NUM + e1] + r1;
    rowlist[p0] = t;
    rowlist[p1] = t;
    posv[t] = p0 | (p1 << 16);
}

// ---- combine: out[t] = ybuf[p0] + ybuf[p1] + b2[e0] + b2[e1] ----
__global__ void combine_kernel(const int* __restrict__ top2, const int* __restrict__ posv,
                               const unsigned short* __restrict__ ybuf, const float* __restrict__ b2,
                               float* __restrict__ out) {
    int t = blockIdx.x;
    int v = top2[t];
    int p = posv[t];
    int e0 = v & 255, e1 = v >> 8;
    int p0 = p & 0xffff, p1 = (p >> 16) & 0xffff;
    int i = threadIdx.x;  // 256 threads x 4 elems
    const ushort4* y0 = (const ushort4*)(ybuf + (size_t)p0 * H_DIM);
    const ushort4* y1 = (const ushort4*)(ybuf + (size_t)p1 * H_DIM);
    const float4* q0 = (const float4*)(b2 + (size_t)e0 * H_DIM);
    const float4* q1 = (const float4*)(b2 + (size_t)e1 * H_DIM);
    ushort4 a = y0[i], b = y1[i];
    float4 c0 = q0[i], c1 = q1[i];
    float4 o;
    o.x = bf2f(a.x) + bf2f(b.x) + c0.x + c1.x;
    o.y = bf2f(a.y) + bf2f(b.y) + c0.y + c1.y;
    o.z = bf2f(a.z) + bf2f(b.z) + c0.z + c1.z;
    o.w = bf2f(a.w) + bf2f(b.w) + c0.w + c1.w;
    ((float4*)(out + (size_t)t * H_DIM))[i] = o;
}

// =====================================================================================
// Grouped GEMM, 128x128 tile, BK=64, 4 waves (2Mx2N of 64x64), 2 blocks/CU,
// TILE-LEVEL PING-PONG: ds_reads for tile t+1 issue BEFORE tile t's MFMA cluster and
// drain under it (lgkmcnt(0) only after the MFMA). This is the overlap r3/r5's
// per-phase lgkmcnt(0)-before-MFMA serialized away (25% MfmaUtil across 3 structures).
// Two named fragment generations (fa0/fb0, fa1/fb1; 128 VGPR) + acc 64 -> fits 256.
//
// Per K-tile t (2 barriers, counted vmcnt, never 0 mid-loop):
//   barrier                      // all waves drained reads(t) [lgkm(0) end of t-1] -> WAR ok
//   stage(t+2 -> buf[t&1])       // 8 gl_lds (A 16KB + B 16KB)
//   vmcnt(8); barrier            // own+all waves' stage(t+1) retired (8 = t+2's in flight)
//   READ16(next <- buf[(t+1)&1]) // 16 ds_read_b128, NO wait
//   MFMA32(cur)                  // 512 cyc/wave hides the read drain
//   lgkmcnt(0)                   // next-set ready for tile t+1
// Ledger invariant: outstanding = 8 (tile t+1's stages) at every tile entry; tail
// t==NKT-2 uses vmcnt(0) (drains last stage), t==NKT-1 skips stage/read.
// XOR chunk swizzle (LDS[r][c] = global chunk c^(r&7)) as verified in r3/r5: 0 conflicts.
// Block mapping: bid&7 = expert -> XCD; expert weight panel stays L2-resident per XCD.
// =====================================================================================
template<int KD, int NTILES_N, bool IS_G1>
__global__ __launch_bounds__(256, 2)
void gemm_pp(const unsigned short* __restrict__ A,    // xb [T,H] (G1) or h1 [2T,F] (G2)
             const unsigned short* __restrict__ Bt,   // w1t [E,F,H] or w2t [E,H,F]  (B^T)
             const float* __restrict__ bias_p,        // b1 [E,F] (G1) or unused
             const int* __restrict__ rowlist,
             const int* __restrict__ basep,
             const int* __restrict__ counts,
             unsigned short* __restrict__ Out)        // h1 [2T,F] or ybuf [2T,H]
{
    constexpr int ND = NTILES_N * GBN;
    constexpr int NKT = KD / GBK;
    static_assert(NKT >= 4 && (NKT & 1) == 0, "pipeline needs even NKT >= 4");

    int bid = blockIdx.x;
    int e = bid & 7;
    int q = bid >> 3;
    int nt = q % NTILES_N;
    int mt = q / NTILES_N;
    int n_e = counts[e];
    if (mt * GBM >= n_e) return;
    int base_e = basep[e];

    __shared__ __attribute__((aligned(16))) unsigned char lds[2][32768];

    int tid = threadIdx.x;
    int wv = tid >> 6, lane = tid & 63;

    // ---- staging sources: thread stages rows srow+{0,32,64,96}, swizzled chunk gc ----
    int srow = tid >> 3;                       // 0..31
    int gc = (tid & 7) ^ (srow & 7);           // global 16B chunk this thread fetches
    const unsigned short* aS[4];
    const unsigned short* bS[4];
#pragma unroll
    for (int i = 0; i < 4; i++) {
        int r = srow + i * 32;
        size_t ra;
        if (IS_G1) {
            int rr = min(mt * GBM + r, n_e - 1);
            ra = (size_t)rowlist[base_e + rr];
        } else {
            ra = (size_t)(base_e + min(mt * GBM + r, n_e - 1));
        }
        aS[i] = A + ra * KD + gc * 8;
        bS[i] = Bt + ((size_t)e * ND + nt * GBN + r) * KD + gc * 8;
    }

    // full-tile stage: 8 gl_lds (A rows 0..127 then B rows 0..127), buf = 0/1
    auto stage_full = [&](int t, int buf) {
        char* d = (char*)lds + buf * 32768 + wv * 1024;
#pragma unroll
        for (int i = 0; i < 4; i++) gl_lds16(aS[i] + t * GBK, d + i * 4096);
#pragma unroll
        for (int i = 0; i < 4; i++) gl_lds16(bS[i] + t * GBK, d + 16384 + i * 4096);
    };

    // ---- reader geometry ----
    int mlane = lane & 15, quad = lane >> 4;
    int wr = (wv >> 1) * 64;    // wave M base
    int wc = (wv & 1) * 64;     // wave N base
    int xk0 = (quad * 16) ^ ((mlane & 7) << 4);
    int xk1 = (64 + quad * 16) ^ ((mlane & 7) << 4);
    int aRow = (wr + mlane) * 128;            // + mi*2048 + xk[ks]
    int bRow = 16384 + (wc + mlane) * 128;    // + ni*2048 + xk[ks]

    f32x4 acc[4][4] = {};
    bf16x8 fa0[4][2], fb0[4][2], fa1[4][2], fb1[4][2];

#define READ16(FA, FB, BUFI) do {                                                  \
    const char* _b = (const char*)lds + (BUFI) * 32768;                            \
    _Pragma("unroll")                                                              \
    for (int mi = 0; mi < 4; mi++) {                                               \
        FA[mi][0] = *(const bf16x8*)(_b + aRow + mi * 2048 + xk0);                 \
        FA[mi][1] = *(const bf16x8*)(_b + aRow + mi * 2048 + xk1);                 \
    }                                                                              \
    _Pragma("unroll")                                                              \
    for (int ni = 0; ni < 4; ni++) {                                               \
        FB[ni][0] = *(const bf16x8*)(_b + bRow + ni * 2048 + xk0);                 \
        FB[ni][1] = *(const bf16x8*)(_b + bRow + ni * 2048 + xk1);                 \
    }                                                                              \
} while (0)

#define MFMA32(FA, FB) do {                                                        \
    __builtin_amdgcn_s_setprio(1);                                                 \
    _Pragma("unroll")                                                              \
    for (int ks = 0; ks < 2; ks++)                                                 \
        _Pragma("unroll")                                                          \
        for (int mi = 0; mi < 4; mi++)                                             \
            _Pragma("unroll")                                                      \
            for (int ni = 0; ni < 4; ni++)                                         \
                acc[mi][ni] = __builtin_amdgcn_mfma_f32_16x16x32_bf16(             \
                    FA[mi][ks], FB[ni][ks], acc[mi][ni], 0, 0, 0);                 \
    __builtin_amdgcn_s_setprio(0);                                                 \
} while (0)

#define TILE_BODY(T, BUFC, CA, CB, NA, NB) do {                                    \
    __builtin_amdgcn_s_barrier();                      /* WAR: reads(T) drained */ \
    __builtin_amdgcn_sched_barrier(0);                                             \
    if ((T) + 2 < NKT) stage_full((T) + 2, (BUFC));                                \
    if ((T) + 1 < NKT) {                                                           \
        if ((T) + 2 < NKT) { asm volatile("s_waitcnt vmcnt(8)" ::: "memory"); }    \
        else               { asm volatile("s_waitcnt vmcnt(0)" ::: "memory"); }    \
        __builtin_amdgcn_s_barrier();                  /* tile T+1 resident */     \
        __builtin_amdgcn_sched_barrier(0);                                         \
        READ16(NA, NB, (BUFC) ^ 1);                    /* no wait: drains under */ \
    }                                                                              \
    MFMA32(CA, CB);                                                                \
    asm volatile("s_waitcnt lgkmcnt(0)" ::: "memory"); /* next set ready */        \
    __builtin_amdgcn_sched_barrier(0);                                             \
} while (0)

    // ---- prologue: stage tiles 0,1; wait tile0; read tile0 frags ----
    stage_full(0, 0);
    stage_full(1, 1);
    asm volatile("s_waitcnt vmcnt(8)" ::: "memory");   // tile0's 8 retired
    __builtin_amdgcn_s_barrier();
    __builtin_amdgcn_sched_barrier(0);
    READ16(fa0, fb0, 0);
    asm volatile("s_waitcnt lgkmcnt(0)" ::: "memory");
    __builtin_amdgcn_sched_barrier(0);

    for (int t2 = 0; t2 < NKT; t2 += 2) {
        TILE_BODY(t2,     0, fa0, fb0, fa1, fb1);
        TILE_BODY(t2 + 1, 1, fa1, fb1, fa0, fb0);
    }

#undef TILE_BODY
#undef MFMA32
#undef READ16

    // ---- epilogue ----
    float bias[4];
#pragma unroll
    for (int ni = 0; ni < 4; ni++) {
        if (IS_G1) bias[ni] = bias_p[(size_t)e * ND + nt * GBN + wc + ni * 16 + mlane];
        else bias[ni] = 0.f;
    }
#pragma unroll
    for (int mi = 0; mi < 4; mi++) {
        int mbase = mt * GBM + wr + mi * 16 + quad * 4;
#pragma unroll
        for (int r = 0; r < 4; r++) {
            int m = mbase + r;
            if (m < n_e) {
                unsigned short* orow = Out + (size_t)(base_e + m) * ND + nt * GBN + wc + mlane;
#pragma unroll
                for (int ni = 0; ni < 4; ni++) {
                    float c = acc[mi][ni][r] + bias[ni];
                    if (IS_G1) c = c / (1.f + __expf(-c));
                    orow[ni * 16] = f2bf(c);
                }
            }
        }
    }
}

extern "C" void kernel_launch(void* const* d_in, const int* in_sizes, int n_in,
                              void* d_out, int out_size, void* d_ws, size_t ws_size,
                              hipStream_t stream) {
    const float* x = (const float*)d_in[0];
    const float* rw = (const float*)d_in[1];
    const float* w1 = (const float*)d_in[2];
    const float* b1 = (const float*)d_in[3];
    const float* w2 = (const float*)d_in[4];
    const float* b2 = (const float*)d_in[5];
    float* out = (float*)d_out;

    char* ws = (char*)d_ws;
    int* counts      = (int*)(ws + 0);          // 8 ints
    int* basep       = (int*)(ws + 64);         // 8 ints
    int* blockcounts = (int*)(ws + 128);        // 32*8 ints
    int* offs        = (int*)(ws + 2048);       // 32*8 ints
    float2* loss_part = (float2*)(ws + 4096);   // 2048 float2
    int* top2        = (int*)(ws + 32768);      // 8192 ints
    int* rowlist     = (int*)(ws + 65536);      // 16384 ints = 64 KB
    int* posv        = (int*)(ws + 131072);     // 8192 ints = 32 KB
    unsigned short* xb  = (unsigned short*)(ws + 163840);
    unsigned short* w1t = (unsigned short*)(ws + 163840 + 16777216ULL);
    unsigned short* w2t = (unsigned short*)(ws + 163840 + 16777216ULL + 33554432ULL);
    unsigned short* h1  = (unsigned short*)(ws + 163840 + 16777216ULL + 2ULL * 33554432ULL);
    unsigned short* ybuf = w1t;  // w1t (32 MB) is dead after gemm1; reuse for y [2T,H] bf16

    transpose_conv_kernel<<<dim3(64, 32, 8), 256, 0, stream>>>(w1, w1t, H_DIM, F_DIM);
    transpose_conv_kernel<<<dim3(32, 64, 8), 256, 0, stream>>>(w2, w2t, F_DIM, H_DIM);
    router_kernel<<<T_TOK / 4, 256, 0, stream>>>(x, rw, xb, top2, loss_part);
    hist_kernel<<<NBLK_TOK, 256, 0, stream>>>(top2, blockcounts);
    scan_kernel<<<1, 256, 0, stream>>>(blockcounts, loss_part, counts, basep, offs,
                                       out + (size_t)T_TOK * H_DIM);
    scatter_kernel<<<NBLK_TOK, 256, 0, stream>>>(top2, offs, rowlist, posv);
    // G1: K=H_DIM(1024) -> NKT=16; N=F_DIM => 16 n-tiles; grid = 8*18*16 = 2304
    gemm_pp<H_DIM, F_DIM / GBN, true><<<8 * MT_CAP * (F_DIM / GBN), 256, 0, stream>>>(
        xb, w1t, b1, rowlist, basep, counts, h1);
    // G2: K=F_DIM(2048) -> NKT=32; N=H_DIM => 8 n-tiles; grid = 8*18*8 = 1152
    gemm_pp<F_DIM, H_DIM / GBN, false><<<8 * MT_CAP * (H_DIM / GBN), 256, 0, stream>>>(
        h1, w2t, nullptr, rowlist, basep, counts, ybuf);
    combine_kernel<<<T_TOK, 256, 0, stream>>>(top2, posv, ybuf, b2, out);
}

// Round 8
// 391.442 us; speedup vs baseline: 1.5360x; 1.5360x over previous
//
#include <hip/hip_runtime.h>
#include <stdint.h>

#define T_TOK 8192
#define H_DIM 1024
#define E_NUM 8
#define F_DIM 2048
#define BATCH 4
#define AUX_COEF 0.001f
#define Z_COEF 0.001f

#define NBLK_TOK 32       // blocks for hist/scatter (8192/256)

// ---- grouped GEMM params: 128x128 tile, 4 waves, 2 blocks/CU co-resident ----
#define GBM 128
#define GBN 128
#define GBK 64
#define MT_CAP 18         // 18*128 = 2304 rows capacity per expert (counts ~2048±55)

typedef __bf16 bf16x8 __attribute__((ext_vector_type(8)));
typedef float f32x4 __attribute__((ext_vector_type(4)));

__device__ __forceinline__ unsigned short f2bf(float f) {
    union { float f; uint32_t u; } v; v.f = f;
    uint32_t u = v.u;
    return (unsigned short)((u + 0x7FFFu + ((u >> 16) & 1u)) >> 16);
}
__device__ __forceinline__ float bf2f(unsigned short u) {
    union { uint32_t u; float f; } v; v.u = ((uint32_t)u) << 16; return v.f;
}

// async global->LDS, 16 B per lane; LDS dest = wave-uniform base + lane*16
__device__ __forceinline__ void gl_lds16(const void* g, void* l) {
    __builtin_amdgcn_global_load_lds((const __attribute__((address_space(1))) uint32_t*)g,
                                     (__attribute__((address_space(3))) uint32_t*)l, 16, 0, 0);
}

// ------------- transpose+convert: in [E,R,C] fp32 -> out [E,C,R] bf16 -------------
__global__ void transpose_conv_kernel(const float* __restrict__ in, unsigned short* __restrict__ out,
                                      int R, int C) {
    __shared__ float tile[32][33];
    int e = blockIdx.z;
    const float* ine = in + (size_t)e * R * C;
    unsigned short* oute = out + (size_t)e * R * C;
    int tx = threadIdx.x & 31, ty = threadIdx.x >> 5;  // 32x8
    int c0 = blockIdx.x * 32, r0 = blockIdx.y * 32;
#pragma unroll
    for (int i = 0; i < 4; i++) {
        int r = r0 + ty + i * 8;
        tile[ty + i * 8][tx] = ine[(size_t)r * C + c0 + tx];
    }
    __syncthreads();
#pragma unroll
    for (int i = 0; i < 4; i++) {
        int c = c0 + ty + i * 8;
        oute[(size_t)c * R + r0 + tx] = f2bf(tile[tx][ty + i * 8]);
    }
}

// ------- router (fused x->bf16 convert): logits, losses (block-partial), top-2 -------
__global__ void router_kernel(const float* __restrict__ x, const float* __restrict__ rw,
                              unsigned short* __restrict__ xb,
                              int* __restrict__ top2, float2* __restrict__ loss_part) {
    int wave = threadIdx.x >> 6;
    int lane = threadIdx.x & 63;
    int t = blockIdx.x * 4 + wave;
    const float4* xr = (const float4*)(x + (size_t)t * H_DIM);
    float4 xv[4];
#pragma unroll
    for (int k = 0; k < 4; k++) xv[k] = xr[lane + 64 * k];
    uint2* xo = (uint2*)(xb + (size_t)t * H_DIM);
#pragma unroll
    for (int k = 0; k < 4; k++) {
        uint2 o;
        o.x = (uint32_t)f2bf(xv[k].x) | ((uint32_t)f2bf(xv[k].y) << 16);
        o.y = (uint32_t)f2bf(xv[k].z) | ((uint32_t)f2bf(xv[k].w) << 16);
        xo[lane + 64 * k] = o;
    }
    float acc[E_NUM];
#pragma unroll
    for (int e = 0; e < E_NUM; e++) {
        const float4* rr = (const float4*)(rw + e * H_DIM);
        float s = 0.f;
#pragma unroll
        for (int k = 0; k < 4; k++) {
            float4 r = rr[lane + 64 * k];
            s += xv[k].x * r.x + xv[k].y * r.y + xv[k].z * r.z + xv[k].w * r.w;
        }
        acc[e] = s;
    }
#pragma unroll
    for (int e = 0; e < E_NUM; e++) {
        float v = acc[e];
#pragma unroll
        for (int off = 32; off; off >>= 1) v += __shfl_xor(v, off);
        acc[e] = v;
    }
    __shared__ float red[8];
    if (lane == 0) {
        float mx = acc[0];
#pragma unroll
        for (int e = 1; e < E_NUM; e++) mx = fmaxf(mx, acc[e]);
        float s = 0.f;
#pragma unroll
        for (int e = 0; e < E_NUM; e++) s += expf(acc[e] - mx);
        float lse = mx + logf(s);
        float slogp = 0.f, ssq = 0.f;
#pragma unroll
        for (int e = 0; e < E_NUM; e++) { slogp += acc[e] - lse; ssq += acc[e] * acc[e]; }
        int i1 = 0; float m1 = acc[0];
#pragma unroll
        for (int e = 1; e < E_NUM; e++) if (acc[e] > m1) { m1 = acc[e]; i1 = e; }
        int i2 = -1; float m2 = -1e30f;
#pragma unroll
        for (int e = 0; e < E_NUM; e++) if (e != i1 && acc[e] > m2) { m2 = acc[e]; i2 = e; }
        top2[t] = i1 | (i2 << 8);
        red[wave] = slogp;
        red[4 + wave] = ssq;
    }
    __syncthreads();
    if (threadIdx.x == 0) {
        float2 p;
        p.x = red[0] + red[1] + red[2] + red[3];
        p.y = red[4] + red[5] + red[6] + red[7];
        loss_part[blockIdx.x] = p;
    }
}

// ---------------- histogram: per-block expert counts (LDS bins) ----------------
__global__ void hist_kernel(const int* __restrict__ top2, int* __restrict__ blockcounts) {
    __shared__ int cnt[E_NUM];
    if (threadIdx.x < E_NUM) cnt[threadIdx.x] = 0;
    __syncthreads();
    int t = blockIdx.x * 256 + threadIdx.x;
    int v = top2[t];
    atomicAdd(&cnt[v & 255], 1);
    atomicAdd(&cnt[v >> 8], 1);
    __syncthreads();
    if (threadIdx.x < E_NUM) blockcounts[blockIdx.x * E_NUM + threadIdx.x] = cnt[threadIdx.x];
}

// ---------------- scan + loss finalize (1 block) ----------------
__global__ void scan_kernel(const int* __restrict__ blockcounts, const float2* __restrict__ loss_part,
                            int* __restrict__ counts, int* __restrict__ basep, int* __restrict__ offs,
                            float* __restrict__ loss_out) {
    __shared__ float redx[4], redy[4];
    int tid = threadIdx.x;
    float sx = 0.f, sy = 0.f;
    for (int i = tid; i < T_TOK / 4; i += 256) {
        float2 p = loss_part[i];
        sx += p.x; sy += p.y;
    }
#pragma unroll
    for (int off = 32; off; off >>= 1) { sx += __shfl_xor(sx, off); sy += __shfl_xor(sy, off); }
    if ((tid & 63) == 0) { redx[tid >> 6] = sx; redy[tid >> 6] = sy; }
    __syncthreads();
    if (tid == 0) {
        float slogp = redx[0] + redx[1] + redx[2] + redx[3];
        float ssq = redy[0] + redy[1] + redy[2] + redy[3];
        float ideal = 1.0f / E_NUM;
        float aux = ideal * ((float)T_TOK * E_NUM * logf(ideal) - slogp) / BATCH * AUX_COEF;
        float z = ssq / ((float)T_TOK * E_NUM) * Z_COEF;
        loss_out[0] = aux + z;
    }
    if (tid < E_NUM) {
        int s = 0;
        for (int b = 0; b < NBLK_TOK; b++) s += blockcounts[b * E_NUM + tid];
        counts[tid] = s;
    }
    __syncthreads();
    if (tid == 0) {
        int s = 0;
        for (int e = 0; e < E_NUM; e++) { basep[e] = s; s += counts[e]; }
    }
    __syncthreads();
    if (tid < E_NUM) {
        int o = basep[tid];
        for (int b = 0; b < NBLK_TOK; b++) { offs[b * E_NUM + tid] = o; o += blockcounts[b * E_NUM + tid]; }
    }
}

// -------- scatter: LDS cursors + per-block offsets; record each token's 2 positions --------
__global__ void scatter_kernel(const int* __restrict__ top2, const int* __restrict__ offs,
                               int* __restrict__ rowlist, int* __restrict__ posv) {
    __shared__ int cur[E_NUM];
    if (threadIdx.x < E_NUM) cur[threadIdx.x] = 0;
    __syncthreads();
    int t = blockIdx.x * 256 + threadIdx.x;
    int v = top2[t];
    int e0 = v & 255, e1 = v >> 8;
    int r0 = atomicAdd(&cur[e0], 1);
    int r1 = atomicAdd(&cur[e1], 1);
    int p0 = offs[blockIdx.x * E_NUM + e0] + r0;
    int p1 = offs[blockIdx.x * E_NUM + e1] + r1;
    rowlist[p0] = t;
    rowlist[p1] = t;
    posv[t] = p0 | (p1 << 16);
}

// ---- combine: out[t] = ybuf[p0] + ybuf[p1] + b2[e0] + b2[e1] ----
__global__ void combine_kernel(const int* __restrict__ top2, const int* __restrict__ posv,
                               const unsigned short* __restrict__ ybuf, const float* __restrict__ b2,
                               float* __restrict__ out) {
    int t = blockIdx.x;
    int v = top2[t];
    int p = posv[t];
    int e0 = v & 255, e1 = v >> 8;
    int p0 = p & 0xffff, p1 = (p >> 16) & 0xffff;
    int i = threadIdx.x;  // 256 threads x 4 elems
    const ushort4* y0 = (const ushort4*)(ybuf + (size_t)p0 * H_DIM);
    const ushort4* y1 = (const ushort4*)(ybuf + (size_t)p1 * H_DIM);
    const float4* q0 = (const float4*)(b2 + (size_t)e0 * H_DIM);
    const float4* q1 = (const float4*)(b2 + (size_t)e1 * H_DIM);
    ushort4 a = y0[i], b = y1[i];
    float4 c0 = q0[i], c1 = q1[i];
    float4 o;
    o.x = bf2f(a.x) + bf2f(b.x) + c0.x + c1.x;
    o.y = bf2f(a.y) + bf2f(b.y) + c0.y + c1.y;
    o.z = bf2f(a.z) + bf2f(b.z) + c0.z + c1.z;
    o.w = bf2f(a.w) + bf2f(b.w) + c0.w + c1.w;
    ((float4*)(out + (size_t)t * H_DIM))[i] = o;
}

// =====================================================================================
// Grouped GEMM, 128x128, BK=64, 4 waves (2Mx2N of 64x64), 2 blocks/CU, 4 phases/tile
// with ONE-PHASE-AHEAD reads: each phase's ds_reads feed the NEXT phase's MFMA, so the
// MFMA cluster never waits on a just-issued read (r3/r5's per-phase serializer). Reads
// come FIRST in program order (r6 lesson: stage-before-read makes hipcc insert a vmcnt
// drain before the ds_reads).
//
// Stage halves are FRAG-ALIGNED interleaved row groups:
//   half0 = rows {0-31, 64-95}  = both waves' a01/b01 rows
//   half1 = rows {32-63, 96-127} = both waves' a23/b23 rows
// so a single counted vmcnt gates each read class uniformly for all waves.
//
// Per tile t, phase p: {reads(p+1 frags, 4xb128); sched_barrier; stage(1 half, 2 gl_lds);
//                       8 MFMA (frags drained last phase); lgkmcnt(0); vmcnt(6); barrier}
//   p1: rd b23(t)    | stage Bh1(t+1) | MFMA Q00(a01,b01)
//   p2: rd a23(t)    | stage Ah1(t+1) | MFMA Q01(a01,b23)
//   p3: rd b01'(t+1) | stage Bh0(t+2) | MFMA Q10(a23,b01)
//   p4: rd a01'(t+1) | stage Ah0(t+2) | MFMA Q11(a23,b23)
// vmcnt(6) = 3 halves in flight; every gated region retires 3-4 phases after issue
// (ledger verified incl. prologue vmcnt(4) and peeled tail 6,6,4,2 then 0).
// a01/b01 need two register generations (A/B, swapped per tile parity, compile-time).
// XOR chunk swizzle (LDS[r][c] = chunk c^(r&7)): 0 conflicts (verified r3/r5).
// Block mapping: bid&7 = expert -> XCD; expert weight panel stays L2-resident per XCD.
// =====================================================================================
template<int KD, int NTILES_N, bool IS_G1>
__global__ __launch_bounds__(256, 2)
void gemm_ra(const unsigned short* __restrict__ A,    // xb [T,H] (G1) or h1 [2T,F] (G2)
             const unsigned short* __restrict__ Bt,   // w1t [E,F,H] or w2t [E,H,F]  (B^T)
             const float* __restrict__ bias_p,        // b1 [E,F] (G1) or unused
             const int* __restrict__ rowlist,
             const int* __restrict__ basep,
             const int* __restrict__ counts,
             unsigned short* __restrict__ Out)        // h1 [2T,F] or ybuf [2T,H]
{
    constexpr int ND = NTILES_N * GBN;
    constexpr int NKT = KD / GBK;
    static_assert(NKT >= 4 && (NKT & 1) == 0, "pipeline needs even NKT >= 4");

    int bid = blockIdx.x;
    int e = bid & 7;
    int q = bid >> 3;
    int nt = q % NTILES_N;
    int mt = q / NTILES_N;
    int n_e = counts[e];
    if (mt * GBM >= n_e) return;
    int base_e = basep[e];

    __shared__ __attribute__((aligned(16))) unsigned char lds[2][32768];

    int tid = threadIdx.x;
    int wv = tid >> 6, lane = tid & 63;

    // ---- staging sources: thread stages rows srow+{0,32,64,96}, swizzled chunk gc ----
    int srow = tid >> 3;                       // 0..31
    int gc = (tid & 7) ^ (srow & 7);           // global 16B chunk this thread fetches
    const unsigned short* aS[4];
    const unsigned short* bS[4];
#pragma unroll
    for (int i = 0; i < 4; i++) {
        int r = srow + i * 32;
        size_t ra;
        if (IS_G1) {
            int rr = min(mt * GBM + r, n_e - 1);
            ra = (size_t)rowlist[base_e + rr];
        } else {
            ra = (size_t)(base_e + min(mt * GBM + r, n_e - 1));
        }
        aS[i] = A + ra * KD + gc * 8;
        bS[i] = Bt + ((size_t)e * ND + nt * GBN + r) * KD + gc * 8;
    }

    // stage half h of K-tile t: h=0 -> rows {0-31,64-95} (i=0,2); h=1 -> {32-63,96-127}
    auto stageA = [&](int buf, int h, int t) {
        char* d = (char*)lds + buf * 32768 + wv * 1024;
        gl_lds16(aS[h] + t * GBK,     d + h * 4096);
        gl_lds16(aS[h + 2] + t * GBK, d + (h + 2) * 4096);
    };
    auto stageB = [&](int buf, int h, int t) {
        char* d = (char*)lds + buf * 32768 + 16384 + wv * 1024;
        gl_lds16(bS[h] + t * GBK,     d + h * 4096);
        gl_lds16(bS[h + 2] + t * GBK, d + (h + 2) * 4096);
    };

    // ---- reader geometry ----
    int mlane = lane & 15, quad = lane >> 4;
    int wr = (wv >> 1) * 64;    // wave M base
    int wc = (wv & 1) * 64;     // wave N base
    int xk0 = (quad * 16) ^ ((mlane & 7) << 4);
    int xk1 = (64 + quad * 16) ^ ((mlane & 7) << 4);
    int aRow = (wr + mlane) * 128;            // + mi*2048 + xk[ks]
    int bRow = 16384 + (wc + mlane) * 128;    // + ni*2048 + xk[ks]

    f32x4 acc[4][4] = {};
    bf16x8 a01A[2][2], b01A[2][2], a01B[2][2], b01B[2][2], a23[2][2], b23[2][2];

#define RD_A(DST, MI0, BUF) do {                                                     \
    const char* _p = (const char*)lds + (BUF) * 32768;                               \
    _Pragma("unroll")                                                                \
    for (int mi = 0; mi < 2; mi++) {                                                 \
        DST[mi][0] = *(const bf16x8*)(_p + aRow + ((MI0) + mi) * 2048 + xk0);        \
        DST[mi][1] = *(const bf16x8*)(_p + aRow + ((MI0) + mi) * 2048 + xk1);        \
    }                                                                                \
} while (0)

#define RD_B(DST, NI0, BUF) do {                                                     \
    const char* _p = (const char*)lds + (BUF) * 32768;                               \
    _Pragma("unroll")                                                                \
    for (int ni = 0; ni < 2; ni++) {                                                 \
        DST[ni][0] = *(const bf16x8*)(_p + bRow + ((NI0) + ni) * 2048 + xk0);        \
        DST[ni][1] = *(const bf16x8*)(_p + bRow + ((NI0) + ni) * 2048 + xk1);        \
    }                                                                                \
} while (0)

#define MM(AM, BN, AF, BF) do {                                                      \
    __builtin_amdgcn_s_setprio(1);                                                   \
    _Pragma("unroll")                                                                \
    for (int ks = 0; ks < 2; ks++)                                                   \
        _Pragma("unroll")                                                            \
        for (int mi = 0; mi < 2; mi++)                                               \
            _Pragma("unroll")                                                        \
            for (int ni = 0; ni < 2; ni++)                                           \
                acc[(AM) + mi][(BN) + ni] = __builtin_amdgcn_mfma_f32_16x16x32_bf16( \
                    AF[mi][ks], BF[ni][ks], acc[(AM) + mi][(BN) + ni], 0, 0, 0);     \
    __builtin_amdgcn_s_setprio(0);                                                   \
} while (0)

#define ENDPH(VN) do {                                                               \
    asm volatile("s_waitcnt lgkmcnt(0)" ::: "memory");                               \
    asm volatile("s_waitcnt vmcnt(" #VN ")" ::: "memory");                           \
    __builtin_amdgcn_s_barrier();                                                    \
    __builtin_amdgcn_sched_barrier(0);                                               \
} while (0)

#define TILE(CB, NB, A01C, B01C, A01N, B01N, S1, S2, S3, S4, V1, V2, V3, V4) do {    \
    RD_B(b23, 2, CB); __builtin_amdgcn_sched_barrier(0); S1; MM(0, 0, A01C, B01C); ENDPH(V1); \
    RD_A(a23, 2, CB); __builtin_amdgcn_sched_barrier(0); S2; MM(0, 2, A01C, b23);  ENDPH(V2); \
    RD_B(B01N, 0, NB); __builtin_amdgcn_sched_barrier(0); S3; MM(2, 0, a23, B01C); ENDPH(V3); \
    RD_A(A01N, 0, NB); __builtin_amdgcn_sched_barrier(0); S4; MM(2, 2, a23, b23);  ENDPH(V4); \
} while (0)

    // ---- prologue: tile0 all halves + tile1 half0s; retire tile0; read a01/b01(0) ----
    stageB(0, 0, 0); stageA(0, 0, 0); stageB(0, 1, 0); stageA(0, 1, 0);
    stageB(1, 0, 1); stageA(1, 0, 1);                       // 12 loads
    asm volatile("s_waitcnt vmcnt(4)" ::: "memory");        // tile0 resident; tile1-h0 in flight
    __builtin_amdgcn_s_barrier();
    __builtin_amdgcn_sched_barrier(0);
    RD_A(a01A, 0, 0); RD_B(b01A, 0, 0);
    asm volatile("s_waitcnt lgkmcnt(0)" ::: "memory");
    __builtin_amdgcn_sched_barrier(0);

    // ---- main loop: tiles 0 .. NKT-3 (paired; all stages/reads unconditional) ----
    for (int t2 = 0; t2 + 3 < NKT; t2 += 2) {
        TILE(0, 1, a01A, b01A, a01B, b01B,
             stageB(1, 1, t2 + 1), stageA(1, 1, t2 + 1),
             stageB(0, 0, t2 + 2), stageA(0, 0, t2 + 2), 6, 6, 6, 6);
        TILE(1, 0, a01B, b01B, a01A, b01A,
             stageB(0, 1, t2 + 2), stageA(0, 1, t2 + 2),
             stageB(1, 0, t2 + 3), stageA(1, 0, t2 + 3), 6, 6, 6, 6);
    }
    // ---- tail: tile NKT-2 (stages for NKT-1 only; vmcnt 6,6,4,2) ----
    TILE(0, 1, a01A, b01A, a01B, b01B,
         stageB(1, 1, NKT - 1), stageA(1, 1, NKT - 1),
         (void)0, (void)0, 6, 6, 4, 2);
    // ---- tile NKT-1 (no stages; p3/p4 reads are harmless dead reads; vmcnt 0) ----
    TILE(1, 0, a01B, b01B, a01A, b01A,
         (void)0, (void)0, (void)0, (void)0, 0, 0, 0, 0);

#undef TILE
#undef ENDPH
#undef MM
#undef RD_B
#undef RD_A

    // ---- epilogue ----
    float bias[4];
#pragma unroll
    for (int ni = 0; ni < 4; ni++) {
        if (IS_G1) bias[ni] = bias_p[(size_t)e * ND + nt * GBN + wc + ni * 16 + mlane];
        else bias[ni] = 0.f;
    }
#pragma unroll
    for (int mi = 0; mi < 4; mi++) {
        int mbase = mt * GBM + wr + mi * 16 + quad * 4;
#pragma unroll
        for (int r = 0; r < 4; r++) {
            int m = mbase + r;
            if (m < n_e) {
                unsigned short* orow = Out + (size_t)(base_e + m) * ND + nt * GBN + wc + mlane;
#pragma unroll
                for (int ni = 0; ni < 4; ni++) {
                    float c = acc[mi][ni][r] + bias[ni];
                    if (IS_G1) c = c / (1.f + __expf(-c));
                    orow[ni * 16] = f2bf(c);
                }
            }
        }
    }
}

extern "C" void kernel_launch(void* const* d_in, const int* in_sizes, int n_in,
                              void* d_out, int out_size, void* d_ws, size_t ws_size,
                              hipStream_t stream) {
    const float* x = (const float*)d_in[0];
    const float* rw = (const float*)d_in[1];
    const float* w1 = (const float*)d_in[2];
    const float* b1 = (const float*)d_in[3];
    const float* w2 = (const float*)d_in[4];
    const float* b2 = (const float*)d_in[5];
    float* out = (float*)d_out;

    char* ws = (char*)d_ws;
    int* counts      = (int*)(ws + 0);          // 8 ints
    int* basep       = (int*)(ws + 64);         // 8 ints
    int* blockcounts = (int*)(ws + 128);        // 32*8 ints
    int* offs        = (int*)(ws + 2048);       // 32*8 ints
    float2* loss_part = (float2*)(ws + 4096);   // 2048 float2
    int* top2        = (int*)(ws + 32768);      // 8192 ints
    int* rowlist     = (int*)(ws + 65536);      // 16384 ints = 64 KB
    int* posv        = (int*)(ws + 131072);     // 8192 ints = 32 KB
    unsigned short* xb  = (unsigned short*)(ws + 163840);
    unsigned short* w1t = (unsigned short*)(ws + 163840 + 16777216ULL);
    unsigned short* w2t = (unsigned short*)(ws + 163840 + 16777216ULL + 33554432ULL);
    unsigned short* h1  = (unsigned short*)(ws + 163840 + 16777216ULL + 2ULL * 33554432ULL);
    unsigned short* ybuf = w1t;  // w1t (32 MB) is dead after gemm1; reuse for y [2T,H] bf16

    transpose_conv_kernel<<<dim3(64, 32, 8), 256, 0, stream>>>(w1, w1t, H_DIM, F_DIM);
    transpose_conv_kernel<<<dim3(32, 64, 8), 256, 0, stream>>>(w2, w2t, F_DIM, H_DIM);
    router_kernel<<<T_TOK / 4, 256, 0, stream>>>(x, rw, xb, top2, loss_part);
    hist_kernel<<<NBLK_TOK, 256, 0, stream>>>(top2, blockcounts);
    scan_kernel<<<1, 256, 0, stream>>>(blockcounts, loss_part, counts, basep, offs,
                                       out + (size_t)T_TOK * H_DIM);
    scatter_kernel<<<NBLK_TOK, 256, 0, stream>>>(top2, offs, rowlist, posv);
    // G1: K=H_DIM(1024) -> NKT=16; N=F_DIM => 16 n-tiles; grid = 8*18*16 = 2304
    gemm_ra<H_DIM, F_DIM / GBN, true><<<8 * MT_CAP * (F_DIM / GBN), 256, 0, stream>>>(
        xb, w1t, b1, rowlist, basep, counts, h1);
    // G2: K=F_DIM(2048) -> NKT=32; N=H_DIM => 8 n-tiles; grid = 8*18*8 = 1152
    gemm_ra<F_DIM, H_DIM / GBN, false><<<8 * MT_CAP * (H_DIM / GBN), 256, 0, stream>>>(
        h1, w2t, nullptr, rowlist, basep, counts, ybuf);
    combine_kernel<<<T_TOK, 256, 0, stream>>>(top2, posv, ybuf, b2, out);
}